// Round 1
// baseline (143.643 us; speedup 1.0000x reference)
//
#include <hip/hip_runtime.h>

// RepeatLayers: variable-length repeat_interleave along axis 0.
// Inputs: d_in[0] = encoder_h float32 [N, D], d_in[1] = repeats int32 [N].
// Output: float32 [total_rows, D], total_rows = sum(repeats).
//
// R11: R10 (fill ~70us is harness poison; spread kernel is the remainder,
// below the 69us top-5 cutoff) with three kernel-side cuts:
//  - int4 prologue: prefix re-scan in 16B loads -> <=8 L2 iterations for the
//    latest block (was 16 with int2), ~34 MB aggregate L2 traffic (was 67).
//  - zero-pair early exit: blocks with reps[0]+reps[1]==0 produce no output
//    and skip the prologue + barrier entirely.
//  - non-temporal payload loads and output stores: both streams are
//    single-use (the 456 MB poison fill sweeps L3 every iteration anyway);
//    nt keeps L2 free for the repeats prefix reads and write buffering.
// Everything else (CHUNK=2 / 4096 blocks, loads issued before the prologue,
// one barrier, no atomics, no d_ws) is unchanged from R10.

typedef float nfloat4 __attribute__((ext_vector_type(4)));

#define CHUNK 2
#define BLOCK 256

__global__ __launch_bounds__(BLOCK)
void spread_fused_kernel(const nfloat4* __restrict__ h,
                         const int* __restrict__ repeats,
                         nfloat4* __restrict__ out,
                         int n, int d4 /* = D/4 */) {
    const int c = blockIdx.x;
    const int rbase = c * CHUNK;
    const int t = threadIdx.x;
    const int lane = t & 63;
    const int wave = t >> 6;

    // ---- 1. own repeat counts (one broadcast int2) ----
    int reps[CHUNK];
    if (rbase + CHUNK <= n) {
        const int2 r2 = *(const int2*)(repeats + rbase);
        reps[0] = r2.x; reps[1] = r2.y;
    } else {
#pragma unroll
        for (int j = 0; j < CHUNK; ++j)
            reps[j] = (rbase + j < n) ? repeats[rbase + j] : 0;
    }

    // Blocks with no output rows need neither the prefix sum nor the barrier.
    // (Every block computes its own obase independently, so exiting is safe.)
    if ((reps[0] | reps[1]) == 0) return;

    // ---- 2. issue payload row loads NOW (overlap prologue below) ----
    // d4 == BLOCK for this problem; i-loop runs exactly once.
    const int i = t;  // d4 == 256 == BLOCK (guarded by launch config)
    nfloat4 v[CHUNK];
#pragma unroll
    for (int j = 0; j < CHUNK; ++j) {
        if (reps[j] > 0)                       // block-uniform branch
            v[j] = __builtin_nontemporal_load(&h[(size_t)(rbase + j) * d4 + i]);
    }

    // ---- 3. prologue: obase = sum(repeats[0..rbase)), rbase = 2c ----
    // int4 scan over pairs [0, c - (c&1)); odd tail pair handled by t==0.
    __shared__ int wpart[BLOCK / 64];
    int local = 0;
    {
        const int4* rp4 = (const int4*)repeats;
        const int nq = c >> 1;                 // int4 count covering 2*(c/2) pairs
        for (int q = t; q < nq; q += BLOCK) {  // <=8 L2-hit 16B loads/thread
            const int4 w = rp4[q];
            local += w.x + w.y + w.z + w.w;
        }
        if ((c & 1) && t == 0) {
            const int2 wt = *(const int2*)(repeats + (c - 1) * 2);
            local += wt.x + wt.y;
        }
    }
#pragma unroll
    for (int off = 32; off > 0; off >>= 1)
        local += __shfl_down(local, off, 64);
    if (lane == 0) wpart[wave] = local;
    __syncthreads();
    const int obase = wpart[0] + wpart[1] + wpart[2] + wpart[3];

    int offs[CHUNK];
    offs[0] = obase;
#pragma unroll
    for (int j = 1; j < CHUNK; ++j) offs[j] = offs[j - 1] + reps[j - 1];

    // ---- 4. stores: up to ~14 independent contiguous 4 KB row stores ----
#pragma unroll
    for (int j = 0; j < CHUNK; ++j) {
        const int r = reps[j];
        nfloat4* __restrict__ dst = out + (size_t)offs[j] * d4 + i;
        for (int k = 0; k < r; ++k)
            __builtin_nontemporal_store(v[j], &dst[(size_t)k * d4]);
    }
}

// Generic fallback if d4 != BLOCK (not hit for this problem's shapes).
__global__ __launch_bounds__(BLOCK)
void spread_fused_generic_kernel(const nfloat4* __restrict__ h,
                                 const int* __restrict__ repeats,
                                 nfloat4* __restrict__ out,
                                 int n, int d4) {
    const int c = blockIdx.x;
    const int rbase = c * CHUNK;
    const int t = threadIdx.x;
    const int lane = t & 63;
    const int wave = t >> 6;

    int reps[CHUNK];
#pragma unroll
    for (int j = 0; j < CHUNK; ++j)
        reps[j] = (rbase + j < n) ? repeats[rbase + j] : 0;

    __shared__ int wpart[BLOCK / 64];
    int local = 0;
    const int2* rp2 = (const int2*)repeats;
    for (int q = t; q < c; q += BLOCK) {
        const int2 w = rp2[q];
        local += w.x + w.y;
    }
#pragma unroll
    for (int off = 32; off > 0; off >>= 1)
        local += __shfl_down(local, off, 64);
    if (lane == 0) wpart[wave] = local;
    __syncthreads();
    const int obase = wpart[0] + wpart[1] + wpart[2] + wpart[3];

    int offs[CHUNK];
    offs[0] = obase;
#pragma unroll
    for (int j = 1; j < CHUNK; ++j) offs[j] = offs[j - 1] + reps[j - 1];

    for (int i = t; i < d4; i += BLOCK) {
        nfloat4 v[CHUNK];
#pragma unroll
        for (int j = 0; j < CHUNK; ++j)
            if (reps[j] > 0) v[j] = h[(size_t)(rbase + j) * d4 + i];
#pragma unroll
        for (int j = 0; j < CHUNK; ++j) {
            const int r = reps[j];
            nfloat4* __restrict__ dst = out + (size_t)offs[j] * d4 + i;
            for (int k = 0; k < r; ++k)
                dst[(size_t)k * d4] = v[j];
        }
    }
}

extern "C" void kernel_launch(void* const* d_in, const int* in_sizes, int n_in,
                              void* d_out, int out_size, void* d_ws, size_t ws_size,
                              hipStream_t stream) {
    const float* encoder_h = (const float*)d_in[0];
    const int*   repeats   = (const int*)d_in[1];
    float*       out       = (float*)d_out;

    const int n = in_sizes[1];            // 8192 source rows
    const int d = in_sizes[0] / n;        // 1024 features
    const int d4 = d / 4;

    const int nblocks = (n + CHUNK - 1) / CHUNK;   // 4096
    if (d4 == BLOCK) {
        spread_fused_kernel<<<nblocks, BLOCK, 0, stream>>>(
            (const nfloat4*)encoder_h, repeats, (nfloat4*)out, n, d4);
    } else {
        spread_fused_generic_kernel<<<nblocks, BLOCK, 0, stream>>>(
            (const nfloat4*)encoder_h, repeats, (nfloat4*)out, n, d4);
    }
}